// Round 13
// baseline (334.667 us; speedup 1.0000x reference)
//
#include <hip/hip_runtime.h>
#include <hip/hip_bf16.h>

#define KL  2304   // 48*48
#define KC  64
#define KHS 48
#define KHH 96
#define OFFY (KHS*(KL + 1))    // flat offset for (p+48,q+48)
// padded W-GEMM dims
#define WK   2560              // K: 49*49=2401 padded to 80*32
#define WM   2432              // M: 2401 padded to 19*128

typedef __attribute__((ext_vector_type(8))) short bf16x8;
typedef __attribute__((ext_vector_type(4))) short bf16x4;
typedef __attribute__((ext_vector_type(8))) _Float16 f16x8;
typedef __attribute__((ext_vector_type(4))) float f32x4;

static __device__ inline unsigned short f2bf(float x) {
    __hip_bfloat16 h = __float2bfloat16(x);
    return *reinterpret_cast<unsigned short*>(&h);
}
static __device__ inline float bf2f(unsigned short u) {
    unsigned v = ((unsigned)u) << 16;
    return __uint_as_float(v);
}
static __device__ inline unsigned short f2h(float x) {
    _Float16 h = (_Float16)x;
    return *reinterpret_cast<unsigned short*>(&h);
}

// ---- K0': downsample + |bd|^2 + mask + fp16 x-shift operands (K=192) -------
__global__ __launch_bounds__(64) void k_prep2(const float* __restrict__ f,
    const float* __restrict__ bsrc, const float* __restrict__ mask,
    float* __restrict__ nbuf, float* __restrict__ mdd,
    unsigned short* __restrict__ Ahat, unsigned short* __restrict__ Bhat)
{
    int blk = blockIdx.x;              // nb*KL blocks
    int p = blk % KL, bi = blk / KL;
    int y = p / KHS, x = p % KHS;
    int fy = 2*y + 1;
    int c = threadIdx.x;
    unsigned short* Ap = Ahat + ((size_t)bi*KL + p)*192;
    unsigned short* Bp = Bhat + ((size_t)bi*KL + p)*192;
    float bc = 0.f;
    #pragma unroll
    for (int dxi = 0; dxi < 3; dxi++) {
        int xx = x + dxi - 1;
        float av = 0.f, bv = 0.f;
        if ((unsigned)xx < KHS) {
            int fxx = 2*xx + 1;
            size_t src = (((size_t)bi*KHH + fy)*KHH + fxx)*KC + c;
            av = f[src]; bv = bsrc[src];
        }
        if (dxi == 1) bc = bv;
        Ap[dxi*64 + c] = f2h(av);
        Bp[dxi*64 + c] = f2h(bv);
    }
    float s = bc*bc;
    #pragma unroll
    for (int off = 32; off > 0; off >>= 1) s += __shfl_down(s, off);
    if (c == 0) {
        nbuf[bi*KL + p] = s;
        mdd[bi*KL + p]  = mask[((size_t)bi*KHH + fy)*KHH + (2*x + 1)];
    }
}

// ------- K1: rnrm[q] = 1/max(sqrt(9-tap sum nb),1e-4); mm from mask --------
__global__ __launch_bounds__(256) void k_normmask(const float* __restrict__ nbuf,
    const float* __restrict__ mdd, float* __restrict__ rnrm, float* __restrict__ mm)
{
    int i = blockIdx.x*256 + threadIdx.x;   // nb*KL
    int q = i % KL, bi = i / KL;
    int v = q / KHS, u = q % KHS;
    float sn = 0.f, sm = 0.f;
    for (int dy = -1; dy <= 1; dy++) {
        int vv = v + dy; if ((unsigned)vv >= KHS) continue;
        for (int dx = -1; dx <= 1; dx++) {
            int uu = u + dx; if ((unsigned)uu >= KHS) continue;
            sn += nbuf[bi*KL + vv*KHS + uu];
            sm += mdd[bi*KL + vv*KHS + uu];
        }
    }
    rnrm[i] = 1.0f / fmaxf(sqrtf(sn), 1e-4f);
    mm[i]   = (sm == 0.0f) ? 1.0f : 0.0f;
}

// ------ MFMA GEMM: C = A * B^T, split-K, fp32/bf16 out, fp16/bf16 in, XCD swz
template<int KITERS, bool OUTBF16, bool INFP16>
__global__ __launch_bounds__(256) void k_mfma_bt(const unsigned short* __restrict__ A,
    const unsigned short* __restrict__ B, void* __restrict__ Cv,
    int Ncols, size_t sA, size_t sB, size_t sC, int KDIM, int nsplit, size_t psize)
{
    int flat = blockIdx.x + gridDim.x*(blockIdx.y + gridDim.y*blockIdx.z);
    int nxy = gridDim.x*gridDim.y;
    int total = nxy*gridDim.z;
    int per = total >> 3;
    int g = ((per << 3) == total) ? ((flat & 7)*per + (flat >> 3)) : flat;
    int z = g / nxy; int r = g - z*nxy;
    int by = r / gridDim.x; int bx = r - by*gridDim.x;

    int ks = z % nsplit, bi = z / nsplit;
    int kbase = ks * KITERS * 32;
    int n0 = bx*128, m0 = by*128;
    const unsigned short* Ab = A + (size_t)bi*sA;
    const unsigned short* Bb = B + (size_t)bi*sB;
    __shared__ unsigned short As[128*32];
    __shared__ unsigned short Bs[128*32];
    int t = threadIdx.x;
    int lane = t & 63, w = t >> 6;
    int l15 = lane & 15, quad = lane >> 4;
    int swf = (l15 >> 2) & 3;
    int wm = (w >> 1)*64, wn = (w & 1)*64;
    int srow = lane >> 2;
    int ch = lane & 3;
    f32x4 acc[4][4];
    #pragma unroll
    for (int i = 0; i < 4; i++)
        #pragma unroll
        for (int j = 0; j < 4; j++) acc[i][j] = (f32x4){0.f,0.f,0.f,0.f};

    for (int kk = 0; kk < KITERS; kk++) {
        int k0 = kbase + kk*32;
        #pragma unroll
        for (int i = 0; i < 2; i++) {
            int rbase = w*32 + i*16;
            int r2 = rbase + srow;
            int cs = (ch ^ ((r2 >> 2) & 3))*8;
            const unsigned short* ga = &Ab[(size_t)(m0 + r2)*KDIM + k0 + cs];
            __builtin_amdgcn_global_load_lds(
                (const __attribute__((address_space(1))) void*)ga,
                (__attribute__((address_space(3))) void*)&As[rbase*32], 16, 0, 0);
            const unsigned short* gb = &Bb[(size_t)(n0 + r2)*KDIM + k0 + cs];
            __builtin_amdgcn_global_load_lds(
                (const __attribute__((address_space(1))) void*)gb,
                (__attribute__((address_space(3))) void*)&Bs[rbase*32], 16, 0, 0);
        }
        __syncthreads();
        if (INFP16) {
            f16x8 af[4], bfr[4];
            #pragma unroll
            for (int mi = 0; mi < 4; mi++)
                af[mi] = *(const f16x8*)&As[(wm + mi*16 + l15)*32 + ((quad ^ swf)*8)];
            #pragma unroll
            for (int ni = 0; ni < 4; ni++)
                bfr[ni] = *(const f16x8*)&Bs[(wn + ni*16 + l15)*32 + ((quad ^ swf)*8)];
            #pragma unroll
            for (int mi = 0; mi < 4; mi++)
                #pragma unroll
                for (int ni = 0; ni < 4; ni++)
                    acc[mi][ni] = __builtin_amdgcn_mfma_f32_16x16x32_f16(
                        af[mi], bfr[ni], acc[mi][ni], 0, 0, 0);
        } else {
            bf16x8 af[4], bfr[4];
            #pragma unroll
            for (int mi = 0; mi < 4; mi++)
                af[mi] = *(const bf16x8*)&As[(wm + mi*16 + l15)*32 + ((quad ^ swf)*8)];
            #pragma unroll
            for (int ni = 0; ni < 4; ni++)
                bfr[ni] = *(const bf16x8*)&Bs[(wn + ni*16 + l15)*32 + ((quad ^ swf)*8)];
            #pragma unroll
            for (int mi = 0; mi < 4; mi++)
                #pragma unroll
                for (int ni = 0; ni < 4; ni++)
                    acc[mi][ni] = __builtin_amdgcn_mfma_f32_16x16x32_bf16(
                        af[mi], bfr[ni], acc[mi][ni], 0, 0, 0);
        }
        __syncthreads();
    }
    if (OUTBF16) {
        unsigned short* Cb = (unsigned short*)Cv + (size_t)ks*psize + (size_t)bi*sC;
        #pragma unroll
        for (int mi = 0; mi < 4; mi++)
            #pragma unroll
            for (int ni = 0; ni < 4; ni++) {
                int col = n0 + wn + ni*16 + l15;
                #pragma unroll
                for (int r2 = 0; r2 < 4; r2++) {
                    int row = m0 + wm + mi*16 + quad*4 + r2;
                    Cb[(size_t)row*Ncols + col] = f2bf(acc[mi][ni][r2]);
                }
            }
    } else {
        float* Cb = (float*)Cv + (size_t)ks*psize + (size_t)bi*sC;
        #pragma unroll
        for (int mi = 0; mi < 4; mi++)
            #pragma unroll
            for (int ni = 0; ni < 4; ni++) {
                int col = n0 + wn + ni*16 + l15;
                #pragma unroll
                for (int r2 = 0; r2 < 4; r2++) {
                    int row = m0 + wm + mi*16 + quad*4 + r2;
                    Cb[(size_t)row*Ncols + col] = acc[mi][ni][r2];
                }
            }
    }
}

// ------ K3b v2: y-diagonal 3-tap * rnrm + fuse conv #1 ----------------------
__global__ __launch_bounds__(256) void k_fuse_a2(const float* __restrict__ T,
    const float* __restrict__ rnrm, const float* __restrict__ fw,
    float* __restrict__ Y1)
{
    __shared__ float Sl[10][272];
    int bi = blockIdx.z;
    int qt = blockIdx.x;
    int p0 = blockIdx.y*8, q0 = qt*256;
    const float* Tb = T + (size_t)bi*KL*KL;
    const float* rn = rnrm + bi*KL;
    int t = threadIdx.x;
    bool edge = (qt == 0) | (qt == 8);
    if (!edge) {
        for (int idx = t; idx < 10*66; idx += 256) {
            int r = idx / 66, j = idx - r*66;
            int pp = p0 - 1 + r;
            int qq0 = q0 - 4 + j*4;
            f32x4 s = (f32x4){0.f,0.f,0.f,0.f};
            if ((unsigned)pp < KL) {
                size_t base = (size_t)pp*KL + qq0;
                bool bm = (pp >= KHS), bp = (pp < KL - KHS);
                size_t offm = bm ? (size_t)OFFY : 0;
                size_t offp = bp ? (size_t)OFFY : 0;
                float fm = bm ? 1.f : 0.f, fp2 = bp ? 1.f : 0.f;
                f32x4 v0 = *(const f32x4*)&Tb[base];
                f32x4 vm = *(const f32x4*)&Tb[base - offm];
                f32x4 vp = *(const f32x4*)&Tb[base + offp];
                f32x4 rv = *(const f32x4*)&rn[qq0];
                s = (v0 + fm*vm + fp2*vp) * rv;
            }
            *(f32x4*)&Sl[r][j*4] = s;
        }
    } else {
        for (int idx = t; idx < 10*264; idx += 256) {
            int r = idx / 264, c = idx - r*264;
            int pp = p0 - 1 + r, qq = q0 - 4 + c;
            float s = 0.f;
            if ((unsigned)pp < KL && (unsigned)qq < KL) {
                size_t base = (size_t)pp*KL + qq;
                float acc = Tb[base];
                if (pp >= KHS && qq >= KHS)         acc += Tb[base - OFFY];
                if (pp < KL - KHS && qq < KL - KHS) acc += Tb[base + OFFY];
                s = acc * rn[qq];
            }
            Sl[r][c] = s;
        }
    }
    __syncthreads();
    float w[9];
    #pragma unroll
    for (int i = 0; i < 9; i++) w[i] = fw[i];
    int q = q0 + t;
    float h0[10], h1[10], h2[10];
    #pragma unroll
    for (int r = 0; r < 10; r++) {
        float s0 = Sl[r][t+3], s1 = Sl[r][t+4], s2 = Sl[r][t+5];
        h0[r] = w[0]*s0 + w[1]*s1 + w[2]*s2;
        h1[r] = w[3]*s0 + w[4]*s1 + w[5]*s2;
        h2[r] = w[6]*s0 + w[7]*s1 + w[8]*s2;
    }
    #pragma unroll
    for (int rr = 0; rr < 8; rr++) {
        Y1[((size_t)bi*KL + p0 + rr)*KL + q] = h0[rr] + h1[rr+1] + h2[rr+2];
    }
}

// ------ K5 v4: fuse conv #2 (transposed flat) + softmax -> bf16 -------------
__global__ __launch_bounds__(256) void k_fuse_b(const float* __restrict__ Y1,
    const float* __restrict__ fw, const float* __restrict__ mm,
    unsigned short* __restrict__ Ybf)
{
    __shared__ float rowb[4][KL];   // 36864 B
    __shared__ float red[8];
    int blk = blockIdx.x;           // nb*1152
    int tp0 = (blk % 1152)*2;
    int bi  = blk / 1152;
    int t = threadIdx.x;
    const float* Yb = Y1 + (size_t)bi*KL*KL;
    #pragma unroll
    for (int a = 0; a < 4; a++) {
        int t2 = tp0 - 1 + a;
        float4* dst = (float4*)&rowb[a][0];
        if ((unsigned)t2 < KL) {
            int pr = (t2 % KHS)*KHS + t2/KHS;
            const float4* src = (const float4*)&Yb[(size_t)pr*KL];
            for (int i = t; i < KL/4; i += 256) dst[i] = src[i];
        } else {
            float4 z = {0.f,0.f,0.f,0.f};
            for (int i = t; i < KL/4; i += 256) dst[i] = z;
        }
    }
    float w9[9];
    #pragma unroll
    for (int i = 0; i < 9; i++) w9[i] = fw[i];
    __syncthreads();
    int w = t >> 6, lane = t & 63;
    int half = w >> 1;
    int l128 = t & 127;
    int tp = tp0 + half;
    int x = tp / KHS, y = tp - x*KHS;   // tp = x*48 + y
    int p = y*KHS + x;
    const float* mmb = mm + bi*KL;
    float vals[18];
    float lmax = -1e30f;
    #pragma unroll
    for (int i = 0; i < 18; i++) {
        int q = l128 + i*128;
        int qm = (q >= KHS)      ? q - KHS : 2255 + q;
        int qp = (q <= KL-1-KHS) ? q + KHS : q - 2255;
        float fm = (q != 0)    ? 1.f : 0.f;
        float fp = (q != KL-1) ? 1.f : 0.f;
        float am = w9[0]*rowb[half][qm] + w9[3]*rowb[half+1][qm] + w9[6]*rowb[half+2][qm];
        float a0 = w9[1]*rowb[half][q]  + w9[4]*rowb[half+1][q]  + w9[7]*rowb[half+2][q];
        float ap = w9[2]*rowb[half][qp] + w9[5]*rowb[half+1][qp] + w9[8]*rowb[half+2][qp];
        float val = (fm*am + a0 + fp*ap) * mmb[q] * 10.0f;
        vals[i] = val;
        lmax = fmaxf(lmax, val);
    }
    #pragma unroll
    for (int off = 32; off > 0; off >>= 1) lmax = fmaxf(lmax, __shfl_down(lmax, off));
    if (lane == 0) red[w] = lmax;
    __syncthreads();
    lmax = fmaxf(red[half*2], red[half*2 + 1]);
    float lsum = 0.f;
    #pragma unroll
    for (int i = 0; i < 18; i++) {
        float e = __expf(vals[i] - lmax);
        vals[i] = e;
        lsum += e;
    }
    #pragma unroll
    for (int off = 32; off > 0; off >>= 1) lsum += __shfl_down(lsum, off);
    if (lane == 0) red[4 + w] = lsum;
    __syncthreads();
    lsum = red[4 + half*2] + red[4 + half*2 + 1];
    float inv = 1.0f / lsum;
    unsigned short* orow = Ybf + ((size_t)bi*KL + p)*KL;
    #pragma unroll
    for (int i = 0; i < 18; i++) {
        int q = l128 + i*128;
        orow[q] = f2bf(vals[i]*inv*mmb[q]);
    }
}

// ------ KW: W[(Py,Px),(v',u')] = sum_{a,b} Y[(Py-a,Px-b),(v'-a,u'-b)] -------
// 49x49 padded index space; W row-major [WM rows][WK cols] bf16.
// IMPORTANT: cols 2401..2559 are explicitly zeroed — stale workspace bytes
// reinterpreted as bf16 can be NaN, and NaN*0 = NaN in the downstream GEMM
// (root cause of the round-12 failure).
__global__ __launch_bounds__(256) void k_buildW(const unsigned short* __restrict__ Ybf,
    unsigned short* __restrict__ W)
{
    int blk = blockIdx.x;            // nb*2401
    int row = blk % 2401, bi = blk / 2401;
    int Py = row / 49, Px = row - Py*49;
    const unsigned short* Yb = Ybf + (size_t)bi*KL*KL;
    unsigned short* Wr = W + ((size_t)bi*WM + row)*WK;
    int t = threadIdx.x;
    int w = t >> 6, lane = t & 63;
    for (int vp = w; vp < 49; vp += 4) {
        if (lane < 49) {
            int up = lane;
            float s = 0.f;
            #pragma unroll
            for (int a = 0; a < 2; a++)
                #pragma unroll
                for (int b = 0; b < 2; b++) {
                    int ry = Py - a, rx = Px - b, cv = vp - a, cu = up - b;
                    if ((unsigned)ry < KHS && (unsigned)rx < KHS &&
                        (unsigned)cv < KHS && (unsigned)cu < KHS)
                        s += bf2f(Yb[(size_t)(ry*KHS + rx)*KL + cv*KHS + cu]);
                }
            Wr[vp*49 + up] = f2bf(s);
        }
    }
    // zero the K-pad tail (cols 2401..2559)
    for (int cpad = 2401 + t; cpad < WK; cpad += 256) Wr[cpad] = 0;
}

// ------ KR0: R0e[n=(py*2+px)*64+c][k=v'*49+u'] = b[2v'+py-1, 2u'+px-1, c] ---
// k >= 2401 -> 0 (exact zero padding).
__global__ __launch_bounds__(256) void k_buildR0e(const float* __restrict__ bsrc,
    unsigned short* __restrict__ R0e)
{
    int blk = blockIdx.x;            // nb*256
    int n = blk % 256, bi = blk / 256;
    int c = n & 63, pp = n >> 6;
    int py = pp >> 1, px = pp & 1;
    unsigned short* Rr = R0e + ((size_t)bi*256 + n)*WK;
    for (int k = threadIdx.x; k < WK; k += 256) {
        float val = 0.f;
        if (k < 2401) {
            int vp = k / 49, up = k - vp*49;
            int ry = 2*vp + py - 1, rx = 2*up + px - 1;
            if ((unsigned)ry < KHH && (unsigned)rx < KHH)
                val = bsrc[(((size_t)bi*KHH + ry)*KHH + rx)*KC + c];
        }
        Rr[k] = f2bf(val);
    }
}

// ------ K8': out[iy,ix,c] = 0.25 * sum_{s<8} Pq[s][(Py*49+Px), (py,px,c)] ---
__global__ __launch_bounds__(256) void k_reduce_out(const unsigned short* __restrict__ Pq,
    float* __restrict__ out, size_t psize)
{
    size_t gid = (size_t)blockIdx.x*256 + threadIdx.x;   // nb*96*96*16
    int c4 = (int)(gid & 15)*4;
    size_t r = gid >> 4;
    int ix = (int)(r % KHH); r /= KHH;
    int iy = (int)(r % KHH);
    int bi = (int)(r / KHH);
    int py = (iy & 1) ? 0 : 1;
    int Py = (iy + 1 - py) >> 1;
    int px = (ix & 1) ? 0 : 1;
    int Px = (ix + 1 - px) >> 1;
    size_t base = ((size_t)bi*WM + Py*49 + Px)*256 + ((py*2 + px) << 6) + c4;
    f32x4 acc = (f32x4){0.f,0.f,0.f,0.f};
    #pragma unroll
    for (int s = 0; s < 8; s++) {
        bf16x4 v = *(const bf16x4*)&Pq[base + (size_t)s*psize];
        #pragma unroll
        for (int j = 0; j < 4; j++)
            acc[j] += bf2f((unsigned short)v[j]);
    }
    f32x4 o = acc * 0.25f;
    *(f32x4*)&out[(((size_t)bi*KHH + iy)*KHH + ix)*KC + c4] = o;
}

extern "C" void kernel_launch(void* const* d_in, const int* in_sizes, int n_in,
                              void* d_out, int out_size, void* d_ws, size_t ws_size,
                              hipStream_t stream)
{
    const float* f    = (const float*)d_in[0];
    const float* b    = (const float*)d_in[1];
    const float* mask = (const float*)d_in[2];
    const float* fw   = (const float*)d_in[3];
    float* out = (float*)d_out;

    auto need = [](int nbc) -> size_t {
        return (size_t)nbc * (2ull*KL*KC + 4ull*KL + 2ull*(size_t)KL*KL) * 4ull;
    };
    int nbc = 4;
    if (need(nbc) > ws_size) nbc = 2;
    if (need(nbc) > ws_size) nbc = 1;

    for (int bi0 = 0; bi0 < 4; bi0 += nbc) {
        int nb = (4 - bi0 < nbc) ? (4 - bi0) : nbc;
        const float* fc = f    + (size_t)bi0*KHH*KHH*KC;
        const float* bc = b    + (size_t)bi0*KHH*KHH*KC;
        const float* mc = mask + (size_t)bi0*KHH*KHH;
        float* outc = out + (size_t)bi0*KHH*KHH*KC;

        float* w    = (float*)d_ws;
        float* nbuf = w;  w += (size_t)nbc*KL;
        float* mdd  = w;  w += (size_t)nbc*KL;
        float* rnrm = w;  w += (size_t)nbc*KL;
        float* mmb  = w;  w += (size_t)nbc*KL;
        float* bufA = w;  w += (size_t)nbc*KL*KL;
        float* bufB = w;
        // lifetimes:
        //  bufB: [Ahat|Bhat] (fp16) -> Y1 (fp32) -> [W bf16 | R0e bf16]
        //  bufA: T (fp32) -> Ybf (bf16) -> Pq partials (bf16, after Ybf)
        unsigned short* Ahat = (unsigned short*)bufB;
        unsigned short* Bhat = Ahat + (size_t)nbc*KL*192;
        float* Tbuf = bufA;
        float* Y1   = bufB;
        unsigned short* Ybf = (unsigned short*)bufA;
        unsigned short* Wb  = (unsigned short*)bufB;
        unsigned short* R0e = Wb + (size_t)nbc*WM*WK;
        unsigned short* Pq  = Ybf + (size_t)nbc*KL*KL;  // after Ybf (Ybf dead post-buildW)
        size_t psize = (size_t)nbc*WM*256;   // one split-K partial (elements)

        k_prep2     <<<nb*KL, 64, 0, stream>>>(fc, bc, mc, nbuf, mdd, Ahat, Bhat);
        k_normmask  <<<(nb*KL)/256, 256, 0, stream>>>(nbuf, mdd, rnrm, mmb);
        // T = Ahat * Bhat^T  (K=192 fp16 single-segment, fp32 out)
        k_mfma_bt<6,false,true><<<dim3(18, 18, nb), 256, 0, stream>>>(
            Ahat, Bhat, Tbuf, KL, (size_t)KL*192, (size_t)KL*192, (size_t)KL*KL,
            192, 1, 0);
        // y-diag 3-tap * rnrm + fuse1: T (bufA) -> Y1 (bufB)
        k_fuse_a2   <<<dim3(9, 288, nb), 256, 0, stream>>>(Tbuf, rnrm, fw, Y1);
        // fuse2 + softmax: Y1 (bufB) -> Ybf (bufA)
        k_fuse_b    <<<nb*1152, 256, 0, stream>>>(Y1, fw, mmb, Ybf);
        // W = 2x2 diag box-sum of Y on padded 49x49 grid: Ybf -> W (bufB)
        k_buildW    <<<nb*2401, 256, 0, stream>>>(Ybf, Wb);
        // R0e: 256 parity columns of conv_transpose kernel (exact zero pad)
        k_buildR0e  <<<nb*256, 256, 0, stream>>>(bc, R0e);
        // Pq = W * R0e^T (M=2432, N=256, K=2560, split-K=8, bf16 partials)
        k_mfma_bt<10,true,false><<<dim3(2, 19, nb*8), 256, 0, stream>>>(
            Wb, R0e, Pq, 256, (size_t)WM*WK, (size_t)256*WK, (size_t)WM*256,
            WK, 8, psize);
        // reduce split-K partials + parity scatter + /4 -> out
        k_reduce_out<<<nb*KHH*KHH*16/256, 256, 0, stream>>>(Pq, outc, psize);
    }
}

// Round 14
// 326.571 us; speedup vs baseline: 1.0248x; 1.0248x over previous
//
#include <hip/hip_runtime.h>
#include <hip/hip_bf16.h>

#define KL  2304   // 48*48
#define KC  64
#define KHS 48
#define KHH 96
#define OFFY (KHS*(KL + 1))    // flat offset for (p+48,q+48)
// padded W-GEMM dims
#define WK   2560              // K: 49*49=2401 padded to 80*32
#define WM   2432              // M: 2401 padded to 19*128

typedef __attribute__((ext_vector_type(8))) short bf16x8;
typedef __attribute__((ext_vector_type(4))) short bf16x4;
typedef __attribute__((ext_vector_type(8))) _Float16 f16x8;
typedef __attribute__((ext_vector_type(4))) float f32x4;

static __device__ inline unsigned short f2bf(float x) {
    __hip_bfloat16 h = __float2bfloat16(x);
    return *reinterpret_cast<unsigned short*>(&h);
}
static __device__ inline float bf2f(unsigned short u) {
    unsigned v = ((unsigned)u) << 16;
    return __uint_as_float(v);
}
static __device__ inline unsigned short f2h(float x) {
    _Float16 h = (_Float16)x;
    return *reinterpret_cast<unsigned short*>(&h);
}

// ---- K0': downsample + |bd|^2 + mask + fp16 x-shift operands (K=192) -------
__global__ __launch_bounds__(64) void k_prep2(const float* __restrict__ f,
    const float* __restrict__ bsrc, const float* __restrict__ mask,
    float* __restrict__ nbuf, float* __restrict__ mdd,
    unsigned short* __restrict__ Ahat, unsigned short* __restrict__ Bhat)
{
    int blk = blockIdx.x;              // nb*KL blocks
    int p = blk % KL, bi = blk / KL;
    int y = p / KHS, x = p % KHS;
    int fy = 2*y + 1;
    int c = threadIdx.x;
    unsigned short* Ap = Ahat + ((size_t)bi*KL + p)*192;
    unsigned short* Bp = Bhat + ((size_t)bi*KL + p)*192;
    float bc = 0.f;
    #pragma unroll
    for (int dxi = 0; dxi < 3; dxi++) {
        int xx = x + dxi - 1;
        float av = 0.f, bv = 0.f;
        if ((unsigned)xx < KHS) {
            int fxx = 2*xx + 1;
            size_t src = (((size_t)bi*KHH + fy)*KHH + fxx)*KC + c;
            av = f[src]; bv = bsrc[src];
        }
        if (dxi == 1) bc = bv;
        Ap[dxi*64 + c] = f2h(av);
        Bp[dxi*64 + c] = f2h(bv);
    }
    float s = bc*bc;
    #pragma unroll
    for (int off = 32; off > 0; off >>= 1) s += __shfl_down(s, off);
    if (c == 0) {
        nbuf[bi*KL + p] = s;
        mdd[bi*KL + p]  = mask[((size_t)bi*KHH + fy)*KHH + (2*x + 1)];
    }
}

// ------- K1: rnrm[q] = 1/max(sqrt(9-tap sum nb),1e-4); mm from mask --------
__global__ __launch_bounds__(256) void k_normmask(const float* __restrict__ nbuf,
    const float* __restrict__ mdd, float* __restrict__ rnrm, float* __restrict__ mm)
{
    int i = blockIdx.x*256 + threadIdx.x;   // nb*KL
    int q = i % KL, bi = i / KL;
    int v = q / KHS, u = q % KHS;
    float sn = 0.f, sm = 0.f;
    for (int dy = -1; dy <= 1; dy++) {
        int vv = v + dy; if ((unsigned)vv >= KHS) continue;
        for (int dx = -1; dx <= 1; dx++) {
            int uu = u + dx; if ((unsigned)uu >= KHS) continue;
            sn += nbuf[bi*KL + vv*KHS + uu];
            sm += mdd[bi*KL + vv*KHS + uu];
        }
    }
    rnrm[i] = 1.0f / fmaxf(sqrtf(sn), 1e-4f);
    mm[i]   = (sm == 0.0f) ? 1.0f : 0.0f;
}

// ------ MFMA GEMM: C = A * B^T, split-K, fp32/bf16 out, fp16/bf16 in, XCD swz
template<int KITERS, bool OUTBF16, bool INFP16>
__global__ __launch_bounds__(256) void k_mfma_bt(const unsigned short* __restrict__ A,
    const unsigned short* __restrict__ B, void* __restrict__ Cv,
    int Ncols, size_t sA, size_t sB, size_t sC, int KDIM, int nsplit, size_t psize)
{
    int flat = blockIdx.x + gridDim.x*(blockIdx.y + gridDim.y*blockIdx.z);
    int nxy = gridDim.x*gridDim.y;
    int total = nxy*gridDim.z;
    int per = total >> 3;
    int g = ((per << 3) == total) ? ((flat & 7)*per + (flat >> 3)) : flat;
    int z = g / nxy; int r = g - z*nxy;
    int by = r / gridDim.x; int bx = r - by*gridDim.x;

    int ks = z % nsplit, bi = z / nsplit;
    int kbase = ks * KITERS * 32;
    int n0 = bx*128, m0 = by*128;
    const unsigned short* Ab = A + (size_t)bi*sA;
    const unsigned short* Bb = B + (size_t)bi*sB;
    __shared__ unsigned short As[128*32];
    __shared__ unsigned short Bs[128*32];
    int t = threadIdx.x;
    int lane = t & 63, w = t >> 6;
    int l15 = lane & 15, quad = lane >> 4;
    int swf = (l15 >> 2) & 3;
    int wm = (w >> 1)*64, wn = (w & 1)*64;
    int srow = lane >> 2;
    int ch = lane & 3;
    f32x4 acc[4][4];
    #pragma unroll
    for (int i = 0; i < 4; i++)
        #pragma unroll
        for (int j = 0; j < 4; j++) acc[i][j] = (f32x4){0.f,0.f,0.f,0.f};

    for (int kk = 0; kk < KITERS; kk++) {
        int k0 = kbase + kk*32;
        #pragma unroll
        for (int i = 0; i < 2; i++) {
            int rbase = w*32 + i*16;
            int r2 = rbase + srow;
            int cs = (ch ^ ((r2 >> 2) & 3))*8;
            const unsigned short* ga = &Ab[(size_t)(m0 + r2)*KDIM + k0 + cs];
            __builtin_amdgcn_global_load_lds(
                (const __attribute__((address_space(1))) void*)ga,
                (__attribute__((address_space(3))) void*)&As[rbase*32], 16, 0, 0);
            const unsigned short* gb = &Bb[(size_t)(n0 + r2)*KDIM + k0 + cs];
            __builtin_amdgcn_global_load_lds(
                (const __attribute__((address_space(1))) void*)gb,
                (__attribute__((address_space(3))) void*)&Bs[rbase*32], 16, 0, 0);
        }
        __syncthreads();
        if (INFP16) {
            f16x8 af[4], bfr[4];
            #pragma unroll
            for (int mi = 0; mi < 4; mi++)
                af[mi] = *(const f16x8*)&As[(wm + mi*16 + l15)*32 + ((quad ^ swf)*8)];
            #pragma unroll
            for (int ni = 0; ni < 4; ni++)
                bfr[ni] = *(const f16x8*)&Bs[(wn + ni*16 + l15)*32 + ((quad ^ swf)*8)];
            #pragma unroll
            for (int mi = 0; mi < 4; mi++)
                #pragma unroll
                for (int ni = 0; ni < 4; ni++)
                    acc[mi][ni] = __builtin_amdgcn_mfma_f32_16x16x32_f16(
                        af[mi], bfr[ni], acc[mi][ni], 0, 0, 0);
        } else {
            bf16x8 af[4], bfr[4];
            #pragma unroll
            for (int mi = 0; mi < 4; mi++)
                af[mi] = *(const bf16x8*)&As[(wm + mi*16 + l15)*32 + ((quad ^ swf)*8)];
            #pragma unroll
            for (int ni = 0; ni < 4; ni++)
                bfr[ni] = *(const bf16x8*)&Bs[(wn + ni*16 + l15)*32 + ((quad ^ swf)*8)];
            #pragma unroll
            for (int mi = 0; mi < 4; mi++)
                #pragma unroll
                for (int ni = 0; ni < 4; ni++)
                    acc[mi][ni] = __builtin_amdgcn_mfma_f32_16x16x32_bf16(
                        af[mi], bfr[ni], acc[mi][ni], 0, 0, 0);
        }
        __syncthreads();
    }
    if (OUTBF16) {
        unsigned short* Cb = (unsigned short*)Cv + (size_t)ks*psize + (size_t)bi*sC;
        #pragma unroll
        for (int mi = 0; mi < 4; mi++)
            #pragma unroll
            for (int ni = 0; ni < 4; ni++) {
                int col = n0 + wn + ni*16 + l15;
                #pragma unroll
                for (int r2 = 0; r2 < 4; r2++) {
                    int row = m0 + wm + mi*16 + quad*4 + r2;
                    Cb[(size_t)row*Ncols + col] = f2bf(acc[mi][ni][r2]);
                }
            }
    } else {
        float* Cb = (float*)Cv + (size_t)ks*psize + (size_t)bi*sC;
        #pragma unroll
        for (int mi = 0; mi < 4; mi++)
            #pragma unroll
            for (int ni = 0; ni < 4; ni++) {
                int col = n0 + wn + ni*16 + l15;
                #pragma unroll
                for (int r2 = 0; r2 < 4; r2++) {
                    int row = m0 + wm + mi*16 + quad*4 + r2;
                    Cb[(size_t)row*Ncols + col] = acc[mi][ni][r2];
                }
            }
    }
}

// ------ K3b v2: y-diagonal 3-tap * rnrm + fuse conv #1 ----------------------
__global__ __launch_bounds__(256) void k_fuse_a2(const float* __restrict__ T,
    const float* __restrict__ rnrm, const float* __restrict__ fw,
    float* __restrict__ Y1)
{
    __shared__ float Sl[10][272];
    int bi = blockIdx.z;
    int qt = blockIdx.x;
    int p0 = blockIdx.y*8, q0 = qt*256;
    const float* Tb = T + (size_t)bi*KL*KL;
    const float* rn = rnrm + bi*KL;
    int t = threadIdx.x;
    bool edge = (qt == 0) | (qt == 8);
    if (!edge) {
        for (int idx = t; idx < 10*66; idx += 256) {
            int r = idx / 66, j = idx - r*66;
            int pp = p0 - 1 + r;
            int qq0 = q0 - 4 + j*4;
            f32x4 s = (f32x4){0.f,0.f,0.f,0.f};
            if ((unsigned)pp < KL) {
                size_t base = (size_t)pp*KL + qq0;
                bool bm = (pp >= KHS), bp = (pp < KL - KHS);
                size_t offm = bm ? (size_t)OFFY : 0;
                size_t offp = bp ? (size_t)OFFY : 0;
                float fm = bm ? 1.f : 0.f, fp2 = bp ? 1.f : 0.f;
                f32x4 v0 = *(const f32x4*)&Tb[base];
                f32x4 vm = *(const f32x4*)&Tb[base - offm];
                f32x4 vp = *(const f32x4*)&Tb[base + offp];
                f32x4 rv = *(const f32x4*)&rn[qq0];
                s = (v0 + fm*vm + fp2*vp) * rv;
            }
            *(f32x4*)&Sl[r][j*4] = s;
        }
    } else {
        for (int idx = t; idx < 10*264; idx += 256) {
            int r = idx / 264, c = idx - r*264;
            int pp = p0 - 1 + r, qq = q0 - 4 + c;
            float s = 0.f;
            if ((unsigned)pp < KL && (unsigned)qq < KL) {
                size_t base = (size_t)pp*KL + qq;
                float acc = Tb[base];
                if (pp >= KHS && qq >= KHS)         acc += Tb[base - OFFY];
                if (pp < KL - KHS && qq < KL - KHS) acc += Tb[base + OFFY];
                s = acc * rn[qq];
            }
            Sl[r][c] = s;
        }
    }
    __syncthreads();
    float w[9];
    #pragma unroll
    for (int i = 0; i < 9; i++) w[i] = fw[i];
    int q = q0 + t;
    float h0[10], h1[10], h2[10];
    #pragma unroll
    for (int r = 0; r < 10; r++) {
        float s0 = Sl[r][t+3], s1 = Sl[r][t+4], s2 = Sl[r][t+5];
        h0[r] = w[0]*s0 + w[1]*s1 + w[2]*s2;
        h1[r] = w[3]*s0 + w[4]*s1 + w[5]*s2;
        h2[r] = w[6]*s0 + w[7]*s1 + w[8]*s2;
    }
    #pragma unroll
    for (int rr = 0; rr < 8; rr++) {
        Y1[((size_t)bi*KL + p0 + rr)*KL + q] = h0[rr] + h1[rr+1] + h2[rr+2];
    }
}

// ------ K5 v4: fuse conv #2 (transposed flat) + softmax -> bf16 -------------
__global__ __launch_bounds__(256) void k_fuse_b(const float* __restrict__ Y1,
    const float* __restrict__ fw, const float* __restrict__ mm,
    unsigned short* __restrict__ Ybf)
{
    __shared__ float rowb[4][KL];   // 36864 B
    __shared__ float red[8];
    int blk = blockIdx.x;           // nb*1152
    int tp0 = (blk % 1152)*2;
    int bi  = blk / 1152;
    int t = threadIdx.x;
    const float* Yb = Y1 + (size_t)bi*KL*KL;
    #pragma unroll
    for (int a = 0; a < 4; a++) {
        int t2 = tp0 - 1 + a;
        float4* dst = (float4*)&rowb[a][0];
        if ((unsigned)t2 < KL) {
            int pr = (t2 % KHS)*KHS + t2/KHS;
            const float4* src = (const float4*)&Yb[(size_t)pr*KL];
            for (int i = t; i < KL/4; i += 256) dst[i] = src[i];
        } else {
            float4 z = {0.f,0.f,0.f,0.f};
            for (int i = t; i < KL/4; i += 256) dst[i] = z;
        }
    }
    float w9[9];
    #pragma unroll
    for (int i = 0; i < 9; i++) w9[i] = fw[i];
    __syncthreads();
    int w = t >> 6, lane = t & 63;
    int half = w >> 1;
    int l128 = t & 127;
    int tp = tp0 + half;
    int x = tp / KHS, y = tp - x*KHS;   // tp = x*48 + y
    int p = y*KHS + x;
    const float* mmb = mm + bi*KL;
    float vals[18];
    float lmax = -1e30f;
    #pragma unroll
    for (int i = 0; i < 18; i++) {
        int q = l128 + i*128;
        int qm = (q >= KHS)      ? q - KHS : 2255 + q;
        int qp = (q <= KL-1-KHS) ? q + KHS : q - 2255;
        float fm = (q != 0)    ? 1.f : 0.f;
        float fp = (q != KL-1) ? 1.f : 0.f;
        float am = w9[0]*rowb[half][qm] + w9[3]*rowb[half+1][qm] + w9[6]*rowb[half+2][qm];
        float a0 = w9[1]*rowb[half][q]  + w9[4]*rowb[half+1][q]  + w9[7]*rowb[half+2][q];
        float ap = w9[2]*rowb[half][qp] + w9[5]*rowb[half+1][qp] + w9[8]*rowb[half+2][qp];
        float val = (fm*am + a0 + fp*ap) * mmb[q] * 10.0f;
        vals[i] = val;
        lmax = fmaxf(lmax, val);
    }
    #pragma unroll
    for (int off = 32; off > 0; off >>= 1) lmax = fmaxf(lmax, __shfl_down(lmax, off));
    if (lane == 0) red[w] = lmax;
    __syncthreads();
    lmax = fmaxf(red[half*2], red[half*2 + 1]);
    float lsum = 0.f;
    #pragma unroll
    for (int i = 0; i < 18; i++) {
        float e = __expf(vals[i] - lmax);
        vals[i] = e;
        lsum += e;
    }
    #pragma unroll
    for (int off = 32; off > 0; off >>= 1) lsum += __shfl_down(lsum, off);
    if (lane == 0) red[4 + w] = lsum;
    __syncthreads();
    lsum = red[4 + half*2] + red[4 + half*2 + 1];
    float inv = 1.0f / lsum;
    unsigned short* orow = Ybf + ((size_t)bi*KL + p)*KL;
    #pragma unroll
    for (int i = 0; i < 18; i++) {
        int q = l128 + i*128;
        orow[q] = f2bf(vals[i]*inv*mmb[q]);
    }
}

// ------ KW v2: W[(Py,Px),(v',u')] = sum_{a,b} Y[(Py-a,Px-b),(v'-a,u'-b)] ----
// Linearized column loop: thread t owns cols t, t+256, ... of one W row.
// The 4 taps are 4 coalesced streams (y00+q, y01+q-1, y10+q-48, y11+q-49);
// writes fully coalesced. Cols >= 2401 write exact 0 (NaN-pad fix kept).
__global__ __launch_bounds__(256) void k_buildW(const unsigned short* __restrict__ Ybf,
    unsigned short* __restrict__ W)
{
    int blk = blockIdx.x;            // nb*2401
    int row = blk % 2401, bi = blk / 2401;
    int Py = row / 49, Px = row - Py*49;
    const unsigned short* Yb = Ybf + (size_t)bi*KL*KL;
    unsigned short* Wr = W + ((size_t)bi*WM + row)*WK;
    bool r00 = (Py < KHS) & (Px < KHS);
    bool r01 = (Py < KHS) & (Px >= 1);
    bool r10 = (Py >= 1)  & (Px < KHS);
    bool r11 = (Py >= 1)  & (Px >= 1);
    const unsigned short* y00 = Yb + (size_t)(Py*KHS + Px)*KL;
    const unsigned short* y01 = y00 - KL;            // (Py, Px-1)
    const unsigned short* y10 = y00 - (size_t)KHS*KL; // (Py-1, Px)
    const unsigned short* y11 = y10 - KL;            // (Py-1, Px-1)
    for (int col = threadIdx.x; col < WK; col += 256) {
        float s = 0.f;
        if (col < 2401) {
            int vp = col / 49, up = col - vp*49;
            int q = vp*KHS + up;
            bool c00 = (vp < KHS) & (up < KHS);
            bool c01 = (vp < KHS) & (up >= 1);
            bool c10 = (vp >= 1)  & (up < KHS);
            bool c11 = (vp >= 1)  & (up >= 1);
            if (r00 & c00) s += bf2f(y00[q]);
            if (r01 & c01) s += bf2f(y01[q - 1]);
            if (r10 & c10) s += bf2f(y10[q - KHS]);
            if (r11 & c11) s += bf2f(y11[q - KHS - 1]);
        }
        Wr[col] = f2bf(s);
    }
}

// ------ KR0: R0e[n=(py*2+px)*64+c][k=v'*49+u'] = b[2v'+py-1, 2u'+px-1, c] ---
// k >= 2401 -> 0 (exact zero padding).
__global__ __launch_bounds__(256) void k_buildR0e(const float* __restrict__ bsrc,
    unsigned short* __restrict__ R0e)
{
    int blk = blockIdx.x;            // nb*256
    int n = blk % 256, bi = blk / 256;
    int c = n & 63, pp = n >> 6;
    int py = pp >> 1, px = pp & 1;
    unsigned short* Rr = R0e + ((size_t)bi*256 + n)*WK;
    for (int k = threadIdx.x; k < WK; k += 256) {
        float val = 0.f;
        if (k < 2401) {
            int vp = k / 49, up = k - vp*49;
            int ry = 2*vp + py - 1, rx = 2*up + px - 1;
            if ((unsigned)ry < KHH && (unsigned)rx < KHH)
                val = bsrc[(((size_t)bi*KHH + ry)*KHH + rx)*KC + c];
        }
        Rr[k] = f2bf(val);
    }
}

// ------ K8': out[iy,ix,c] = 0.25 * sum_{s<8} Pq[s][(Py*49+Px), (py,px,c)] ---
__global__ __launch_bounds__(256) void k_reduce_out(const unsigned short* __restrict__ Pq,
    float* __restrict__ out, size_t psize)
{
    size_t gid = (size_t)blockIdx.x*256 + threadIdx.x;   // nb*96*96*16
    int c4 = (int)(gid & 15)*4;
    size_t r = gid >> 4;
    int ix = (int)(r % KHH); r /= KHH;
    int iy = (int)(r % KHH);
    int bi = (int)(r / KHH);
    int py = (iy & 1) ? 0 : 1;
    int Py = (iy + 1 - py) >> 1;
    int px = (ix & 1) ? 0 : 1;
    int Px = (ix + 1 - px) >> 1;
    size_t base = ((size_t)bi*WM + Py*49 + Px)*256 + ((py*2 + px) << 6) + c4;
    f32x4 acc = (f32x4){0.f,0.f,0.f,0.f};
    #pragma unroll
    for (int s = 0; s < 8; s++) {
        bf16x4 v = *(const bf16x4*)&Pq[base + (size_t)s*psize];
        #pragma unroll
        for (int j = 0; j < 4; j++)
            acc[j] += bf2f((unsigned short)v[j]);
    }
    f32x4 o = acc * 0.25f;
    *(f32x4*)&out[(((size_t)bi*KHH + iy)*KHH + ix)*KC + c4] = o;
}

extern "C" void kernel_launch(void* const* d_in, const int* in_sizes, int n_in,
                              void* d_out, int out_size, void* d_ws, size_t ws_size,
                              hipStream_t stream)
{
    const float* f    = (const float*)d_in[0];
    const float* b    = (const float*)d_in[1];
    const float* mask = (const float*)d_in[2];
    const float* fw   = (const float*)d_in[3];
    float* out = (float*)d_out;

    auto need = [](int nbc) -> size_t {
        return (size_t)nbc * (2ull*KL*KC + 4ull*KL + 2ull*(size_t)KL*KL) * 4ull;
    };
    int nbc = 4;
    if (need(nbc) > ws_size) nbc = 2;
    if (need(nbc) > ws_size) nbc = 1;

    for (int bi0 = 0; bi0 < 4; bi0 += nbc) {
        int nb = (4 - bi0 < nbc) ? (4 - bi0) : nbc;
        const float* fc = f    + (size_t)bi0*KHH*KHH*KC;
        const float* bc = b    + (size_t)bi0*KHH*KHH*KC;
        const float* mc = mask + (size_t)bi0*KHH*KHH;
        float* outc = out + (size_t)bi0*KHH*KHH*KC;

        float* w    = (float*)d_ws;
        float* nbuf = w;  w += (size_t)nbc*KL;
        float* mdd  = w;  w += (size_t)nbc*KL;
        float* rnrm = w;  w += (size_t)nbc*KL;
        float* mmb  = w;  w += (size_t)nbc*KL;
        float* bufA = w;  w += (size_t)nbc*KL*KL;
        float* bufB = w;
        // lifetimes:
        //  bufB: [Ahat|Bhat] (fp16) -> Y1 (fp32) -> [W bf16 | R0e bf16]
        //  bufA: T (fp32) -> Ybf (bf16) -> Pq partials (bf16, after Ybf)
        unsigned short* Ahat = (unsigned short*)bufB;
        unsigned short* Bhat = Ahat + (size_t)nbc*KL*192;
        float* Tbuf = bufA;
        float* Y1   = bufB;
        unsigned short* Ybf = (unsigned short*)bufA;
        unsigned short* Wb  = (unsigned short*)bufB;
        unsigned short* R0e = Wb + (size_t)nbc*WM*WK;
        unsigned short* Pq  = Ybf + (size_t)nbc*KL*KL;  // after Ybf (Ybf dead post-buildW)
        size_t psize = (size_t)nbc*WM*256;   // one split-K partial (elements)

        k_prep2     <<<nb*KL, 64, 0, stream>>>(fc, bc, mc, nbuf, mdd, Ahat, Bhat);
        k_normmask  <<<(nb*KL)/256, 256, 0, stream>>>(nbuf, mdd, rnrm, mmb);
        // T = Ahat * Bhat^T  (K=192 fp16 single-segment, fp32 out)
        k_mfma_bt<6,false,true><<<dim3(18, 18, nb), 256, 0, stream>>>(
            Ahat, Bhat, Tbuf, KL, (size_t)KL*192, (size_t)KL*192, (size_t)KL*KL,
            192, 1, 0);
        // y-diag 3-tap * rnrm + fuse1: T (bufA) -> Y1 (bufB)
        k_fuse_a2   <<<dim3(9, 288, nb), 256, 0, stream>>>(Tbuf, rnrm, fw, Y1);
        // fuse2 + softmax: Y1 (bufB) -> Ybf (bufA)
        k_fuse_b    <<<nb*1152, 256, 0, stream>>>(Y1, fw, mmb, Ybf);
        // W = 2x2 diag box-sum of Y on padded 49x49 grid: Ybf -> W (bufB)
        k_buildW    <<<nb*2401, 256, 0, stream>>>(Ybf, Wb);
        // R0e: 256 parity columns of conv_transpose kernel (exact zero pad)
        k_buildR0e  <<<nb*256, 256, 0, stream>>>(bc, R0e);
        // Pq = W * R0e^T (M=2432, N=256, K=2560, split-K=8, bf16 partials)
        k_mfma_bt<10,true,false><<<dim3(2, 19, nb*8), 256, 0, stream>>>(
            Wb, R0e, Pq, 256, (size_t)WM*WK, (size_t)256*WK, (size_t)WM*256,
            WK, 8, psize);
        // reduce split-K partials + parity scatter + /4 -> out
        k_reduce_out<<<nb*KHH*KHH*16/256, 256, 0, stream>>>(Pq, outc, psize);
    }
}

// Round 15
// 325.575 us; speedup vs baseline: 1.0279x; 1.0031x over previous
//
#include <hip/hip_runtime.h>
#include <hip/hip_bf16.h>

#define KL  2304   // 48*48
#define KC  64
#define KHS 48
#define KHH 96
#define OFFY (KHS*(KL + 1))    // flat offset for (p+48,q+48)
// padded W-GEMM dims
#define WK   2560              // K: 49*49=2401 padded to 80*32
#define WM   2432              // M: 2401 padded to 19*128

typedef __attribute__((ext_vector_type(8))) short bf16x8;
typedef __attribute__((ext_vector_type(4))) short bf16x4;
typedef __attribute__((ext_vector_type(8))) _Float16 f16x8;
typedef __attribute__((ext_vector_type(4))) float f32x4;

static __device__ inline unsigned short f2bf(float x) {
    __hip_bfloat16 h = __float2bfloat16(x);
    return *reinterpret_cast<unsigned short*>(&h);
}
static __device__ inline float bf2f(unsigned short u) {
    unsigned v = ((unsigned)u) << 16;
    return __uint_as_float(v);
}
static __device__ inline unsigned short f2h(float x) {
    _Float16 h = (_Float16)x;
    return *reinterpret_cast<unsigned short*>(&h);
}

// ---- K0': downsample + |bd|^2 + mask + fp16 x-shift operands (K=192) -------
__global__ __launch_bounds__(64) void k_prep2(const float* __restrict__ f,
    const float* __restrict__ bsrc, const float* __restrict__ mask,
    float* __restrict__ nbuf, float* __restrict__ mdd,
    unsigned short* __restrict__ Ahat, unsigned short* __restrict__ Bhat)
{
    int blk = blockIdx.x;              // nb*KL blocks
    int p = blk % KL, bi = blk / KL;
    int y = p / KHS, x = p % KHS;
    int fy = 2*y + 1;
    int c = threadIdx.x;
    unsigned short* Ap = Ahat + ((size_t)bi*KL + p)*192;
    unsigned short* Bp = Bhat + ((size_t)bi*KL + p)*192;
    float bc = 0.f;
    #pragma unroll
    for (int dxi = 0; dxi < 3; dxi++) {
        int xx = x + dxi - 1;
        float av = 0.f, bv = 0.f;
        if ((unsigned)xx < KHS) {
            int fxx = 2*xx + 1;
            size_t src = (((size_t)bi*KHH + fy)*KHH + fxx)*KC + c;
            av = f[src]; bv = bsrc[src];
        }
        if (dxi == 1) bc = bv;
        Ap[dxi*64 + c] = f2h(av);
        Bp[dxi*64 + c] = f2h(bv);
    }
    float s = bc*bc;
    #pragma unroll
    for (int off = 32; off > 0; off >>= 1) s += __shfl_down(s, off);
    if (c == 0) {
        nbuf[bi*KL + p] = s;
        mdd[bi*KL + p]  = mask[((size_t)bi*KHH + fy)*KHH + (2*x + 1)];
    }
}

// ------- K1: rnrm[q] = 1/max(sqrt(9-tap sum nb),1e-4); mm from mask --------
__global__ __launch_bounds__(256) void k_normmask(const float* __restrict__ nbuf,
    const float* __restrict__ mdd, float* __restrict__ rnrm, float* __restrict__ mm)
{
    int i = blockIdx.x*256 + threadIdx.x;   // nb*KL
    int q = i % KL, bi = i / KL;
    int v = q / KHS, u = q % KHS;
    float sn = 0.f, sm = 0.f;
    for (int dy = -1; dy <= 1; dy++) {
        int vv = v + dy; if ((unsigned)vv >= KHS) continue;
        for (int dx = -1; dx <= 1; dx++) {
            int uu = u + dx; if ((unsigned)uu >= KHS) continue;
            sn += nbuf[bi*KL + vv*KHS + uu];
            sm += mdd[bi*KL + vv*KHS + uu];
        }
    }
    rnrm[i] = 1.0f / fmaxf(sqrtf(sn), 1e-4f);
    mm[i]   = (sm == 0.0f) ? 1.0f : 0.0f;
}

// ------ MFMA GEMM: C = A * B^T, split-K, fp32/bf16 out, fp16/bf16 in, XCD swz
template<int KITERS, bool OUTBF16, bool INFP16>
__global__ __launch_bounds__(256) void k_mfma_bt(const unsigned short* __restrict__ A,
    const unsigned short* __restrict__ B, void* __restrict__ Cv,
    int Ncols, size_t sA, size_t sB, size_t sC, int KDIM, int nsplit, size_t psize)
{
    int flat = blockIdx.x + gridDim.x*(blockIdx.y + gridDim.y*blockIdx.z);
    int nxy = gridDim.x*gridDim.y;
    int total = nxy*gridDim.z;
    int per = total >> 3;
    int g = ((per << 3) == total) ? ((flat & 7)*per + (flat >> 3)) : flat;
    int z = g / nxy; int r = g - z*nxy;
    int by = r / gridDim.x; int bx = r - by*gridDim.x;

    int ks = z % nsplit, bi = z / nsplit;
    int kbase = ks * KITERS * 32;
    int n0 = bx*128, m0 = by*128;
    const unsigned short* Ab = A + (size_t)bi*sA;
    const unsigned short* Bb = B + (size_t)bi*sB;
    __shared__ unsigned short As[128*32];
    __shared__ unsigned short Bs[128*32];
    int t = threadIdx.x;
    int lane = t & 63, w = t >> 6;
    int l15 = lane & 15, quad = lane >> 4;
    int swf = (l15 >> 2) & 3;
    int wm = (w >> 1)*64, wn = (w & 1)*64;
    int srow = lane >> 2;
    int ch = lane & 3;
    f32x4 acc[4][4];
    #pragma unroll
    for (int i = 0; i < 4; i++)
        #pragma unroll
        for (int j = 0; j < 4; j++) acc[i][j] = (f32x4){0.f,0.f,0.f,0.f};

    for (int kk = 0; kk < KITERS; kk++) {
        int k0 = kbase + kk*32;
        #pragma unroll
        for (int i = 0; i < 2; i++) {
            int rbase = w*32 + i*16;
            int r2 = rbase + srow;
            int cs = (ch ^ ((r2 >> 2) & 3))*8;
            const unsigned short* ga = &Ab[(size_t)(m0 + r2)*KDIM + k0 + cs];
            __builtin_amdgcn_global_load_lds(
                (const __attribute__((address_space(1))) void*)ga,
                (__attribute__((address_space(3))) void*)&As[rbase*32], 16, 0, 0);
            const unsigned short* gb = &Bb[(size_t)(n0 + r2)*KDIM + k0 + cs];
            __builtin_amdgcn_global_load_lds(
                (const __attribute__((address_space(1))) void*)gb,
                (__attribute__((address_space(3))) void*)&Bs[rbase*32], 16, 0, 0);
        }
        __syncthreads();
        if (INFP16) {
            f16x8 af[4], bfr[4];
            #pragma unroll
            for (int mi = 0; mi < 4; mi++)
                af[mi] = *(const f16x8*)&As[(wm + mi*16 + l15)*32 + ((quad ^ swf)*8)];
            #pragma unroll
            for (int ni = 0; ni < 4; ni++)
                bfr[ni] = *(const f16x8*)&Bs[(wn + ni*16 + l15)*32 + ((quad ^ swf)*8)];
            #pragma unroll
            for (int mi = 0; mi < 4; mi++)
                #pragma unroll
                for (int ni = 0; ni < 4; ni++)
                    acc[mi][ni] = __builtin_amdgcn_mfma_f32_16x16x32_f16(
                        af[mi], bfr[ni], acc[mi][ni], 0, 0, 0);
        } else {
            bf16x8 af[4], bfr[4];
            #pragma unroll
            for (int mi = 0; mi < 4; mi++)
                af[mi] = *(const bf16x8*)&As[(wm + mi*16 + l15)*32 + ((quad ^ swf)*8)];
            #pragma unroll
            for (int ni = 0; ni < 4; ni++)
                bfr[ni] = *(const bf16x8*)&Bs[(wn + ni*16 + l15)*32 + ((quad ^ swf)*8)];
            #pragma unroll
            for (int mi = 0; mi < 4; mi++)
                #pragma unroll
                for (int ni = 0; ni < 4; ni++)
                    acc[mi][ni] = __builtin_amdgcn_mfma_f32_16x16x32_bf16(
                        af[mi], bfr[ni], acc[mi][ni], 0, 0, 0);
        }
        __syncthreads();
    }
    if (OUTBF16) {
        unsigned short* Cb = (unsigned short*)Cv + (size_t)ks*psize + (size_t)bi*sC;
        #pragma unroll
        for (int mi = 0; mi < 4; mi++)
            #pragma unroll
            for (int ni = 0; ni < 4; ni++) {
                int col = n0 + wn + ni*16 + l15;
                #pragma unroll
                for (int r2 = 0; r2 < 4; r2++) {
                    int row = m0 + wm + mi*16 + quad*4 + r2;
                    Cb[(size_t)row*Ncols + col] = f2bf(acc[mi][ni][r2]);
                }
            }
    } else {
        float* Cb = (float*)Cv + (size_t)ks*psize + (size_t)bi*sC;
        #pragma unroll
        for (int mi = 0; mi < 4; mi++)
            #pragma unroll
            for (int ni = 0; ni < 4; ni++) {
                int col = n0 + wn + ni*16 + l15;
                #pragma unroll
                for (int r2 = 0; r2 < 4; r2++) {
                    int row = m0 + wm + mi*16 + quad*4 + r2;
                    Cb[(size_t)row*Ncols + col] = acc[mi][ni][r2];
                }
            }
    }
}

// ------ K3b v2: y-diagonal 3-tap * rnrm + fuse conv #1 ----------------------
__global__ __launch_bounds__(256) void k_fuse_a2(const float* __restrict__ T,
    const float* __restrict__ rnrm, const float* __restrict__ fw,
    float* __restrict__ Y1)
{
    __shared__ float Sl[10][272];
    int bi = blockIdx.z;
    int qt = blockIdx.x;
    int p0 = blockIdx.y*8, q0 = qt*256;
    const float* Tb = T + (size_t)bi*KL*KL;
    const float* rn = rnrm + bi*KL;
    int t = threadIdx.x;
    bool edge = (qt == 0) | (qt == 8);
    if (!edge) {
        for (int idx = t; idx < 10*66; idx += 256) {
            int r = idx / 66, j = idx - r*66;
            int pp = p0 - 1 + r;
            int qq0 = q0 - 4 + j*4;
            f32x4 s = (f32x4){0.f,0.f,0.f,0.f};
            if ((unsigned)pp < KL) {
                size_t base = (size_t)pp*KL + qq0;
                bool bm = (pp >= KHS), bp = (pp < KL - KHS);
                size_t offm = bm ? (size_t)OFFY : 0;
                size_t offp = bp ? (size_t)OFFY : 0;
                float fm = bm ? 1.f : 0.f, fp2 = bp ? 1.f : 0.f;
                f32x4 v0 = *(const f32x4*)&Tb[base];
                f32x4 vm = *(const f32x4*)&Tb[base - offm];
                f32x4 vp = *(const f32x4*)&Tb[base + offp];
                f32x4 rv = *(const f32x4*)&rn[qq0];
                s = (v0 + fm*vm + fp2*vp) * rv;
            }
            *(f32x4*)&Sl[r][j*4] = s;
        }
    } else {
        for (int idx = t; idx < 10*264; idx += 256) {
            int r = idx / 264, c = idx - r*264;
            int pp = p0 - 1 + r, qq = q0 - 4 + c;
            float s = 0.f;
            if ((unsigned)pp < KL && (unsigned)qq < KL) {
                size_t base = (size_t)pp*KL + qq;
                float acc = Tb[base];
                if (pp >= KHS && qq >= KHS)         acc += Tb[base - OFFY];
                if (pp < KL - KHS && qq < KL - KHS) acc += Tb[base + OFFY];
                s = acc * rn[qq];
            }
            Sl[r][c] = s;
        }
    }
    __syncthreads();
    float w[9];
    #pragma unroll
    for (int i = 0; i < 9; i++) w[i] = fw[i];
    int q = q0 + t;
    float h0[10], h1[10], h2[10];
    #pragma unroll
    for (int r = 0; r < 10; r++) {
        float s0 = Sl[r][t+3], s1 = Sl[r][t+4], s2 = Sl[r][t+5];
        h0[r] = w[0]*s0 + w[1]*s1 + w[2]*s2;
        h1[r] = w[3]*s0 + w[4]*s1 + w[5]*s2;
        h2[r] = w[6]*s0 + w[7]*s1 + w[8]*s2;
    }
    #pragma unroll
    for (int rr = 0; rr < 8; rr++) {
        Y1[((size_t)bi*KL + p0 + rr)*KL + q] = h0[rr] + h1[rr+1] + h2[rr+2];
    }
}

// ------ K5 v4: fuse conv #2 (transposed flat) + softmax -> bf16 -------------
__global__ __launch_bounds__(256) void k_fuse_b(const float* __restrict__ Y1,
    const float* __restrict__ fw, const float* __restrict__ mm,
    unsigned short* __restrict__ Ybf)
{
    __shared__ float rowb[4][KL];   // 36864 B
    __shared__ float red[8];
    int blk = blockIdx.x;           // nb*1152
    int tp0 = (blk % 1152)*2;
    int bi  = blk / 1152;
    int t = threadIdx.x;
    const float* Yb = Y1 + (size_t)bi*KL*KL;
    #pragma unroll
    for (int a = 0; a < 4; a++) {
        int t2 = tp0 - 1 + a;
        float4* dst = (float4*)&rowb[a][0];
        if ((unsigned)t2 < KL) {
            int pr = (t2 % KHS)*KHS + t2/KHS;
            const float4* src = (const float4*)&Yb[(size_t)pr*KL];
            for (int i = t; i < KL/4; i += 256) dst[i] = src[i];
        } else {
            float4 z = {0.f,0.f,0.f,0.f};
            for (int i = t; i < KL/4; i += 256) dst[i] = z;
        }
    }
    float w9[9];
    #pragma unroll
    for (int i = 0; i < 9; i++) w9[i] = fw[i];
    __syncthreads();
    int w = t >> 6, lane = t & 63;
    int half = w >> 1;
    int l128 = t & 127;
    int tp = tp0 + half;
    int x = tp / KHS, y = tp - x*KHS;   // tp = x*48 + y
    int p = y*KHS + x;
    const float* mmb = mm + bi*KL;
    float vals[18];
    float lmax = -1e30f;
    #pragma unroll
    for (int i = 0; i < 18; i++) {
        int q = l128 + i*128;
        int qm = (q >= KHS)      ? q - KHS : 2255 + q;
        int qp = (q <= KL-1-KHS) ? q + KHS : q - 2255;
        float fm = (q != 0)    ? 1.f : 0.f;
        float fp = (q != KL-1) ? 1.f : 0.f;
        float am = w9[0]*rowb[half][qm] + w9[3]*rowb[half+1][qm] + w9[6]*rowb[half+2][qm];
        float a0 = w9[1]*rowb[half][q]  + w9[4]*rowb[half+1][q]  + w9[7]*rowb[half+2][q];
        float ap = w9[2]*rowb[half][qp] + w9[5]*rowb[half+1][qp] + w9[8]*rowb[half+2][qp];
        float val = (fm*am + a0 + fp*ap) * mmb[q] * 10.0f;
        vals[i] = val;
        lmax = fmaxf(lmax, val);
    }
    #pragma unroll
    for (int off = 32; off > 0; off >>= 1) lmax = fmaxf(lmax, __shfl_down(lmax, off));
    if (lane == 0) red[w] = lmax;
    __syncthreads();
    lmax = fmaxf(red[half*2], red[half*2 + 1]);
    float lsum = 0.f;
    #pragma unroll
    for (int i = 0; i < 18; i++) {
        float e = __expf(vals[i] - lmax);
        vals[i] = e;
        lsum += e;
    }
    #pragma unroll
    for (int off = 32; off > 0; off >>= 1) lsum += __shfl_down(lsum, off);
    if (lane == 0) red[4 + w] = lsum;
    __syncthreads();
    lsum = red[4 + half*2] + red[4 + half*2 + 1];
    float inv = 1.0f / lsum;
    unsigned short* orow = Ybf + ((size_t)bi*KL + p)*KL;
    #pragma unroll
    for (int i = 0; i < 18; i++) {
        int q = l128 + i*128;
        orow[q] = f2bf(vals[i]*inv*mmb[q]);
    }
}

// ------ KW v4: W[(Py,Px),(v',u')] = sum_{a,b} Y[(Py-a,Px-b),(v'-a,u'-b)] ----
// Fully unrolled column loop with load/compute phase separation: all 40
// masked gathers issued before any combine/store (ILP ~40 vs v2's 4 —
// v2 was latency-bound at 8 VGPRs). Cols >= 2401 write exact 0 (NaN fix).
__global__ __launch_bounds__(256) void k_buildW(const unsigned short* __restrict__ Ybf,
    unsigned short* __restrict__ W)
{
    int blk = blockIdx.x;            // nb*2401
    int row = blk % 2401, bi = blk / 2401;
    int Py = row / 49, Px = row - Py*49;
    const unsigned short* Yb = Ybf + (size_t)bi*KL*KL;
    unsigned short* Wr = W + ((size_t)bi*WM + row)*WK;
    bool r00 = (Py < KHS) & (Px < KHS);
    bool r01 = (Py < KHS) & (Px >= 1);
    bool r10 = (Py >= 1)  & (Px < KHS);
    bool r11 = (Py >= 1)  & (Px >= 1);
    const unsigned short* y00 = Yb + (size_t)(Py*KHS + Px)*KL;
    const unsigned short* y01 = y00 - KL;             // (Py, Px-1)
    const unsigned short* y10 = y00 - (size_t)KHS*KL; // (Py-1, Px)
    const unsigned short* y11 = y10 - KL;             // (Py-1, Px-1)
    unsigned short v00[10], v01[10], v10[10], v11[10];
    #pragma unroll
    for (int it = 0; it < 10; it++) {
        int col = threadIdx.x + it*256;
        int vp = col / 49, up = col - vp*49;
        int q = vp*KHS + up;
        bool in = (col < 2401);
        bool c0 = (up < KHS), c1 = (up >= 1);
        bool g0 = (vp < KHS), g1 = (vp >= 1);
        v00[it] = (in & r00 & g0 & c0) ? y00[q]           : (unsigned short)0;
        v01[it] = (in & r01 & g0 & c1) ? y01[q - 1]       : (unsigned short)0;
        v10[it] = (in & r10 & g1 & c0) ? y10[q - KHS]     : (unsigned short)0;
        v11[it] = (in & r11 & g1 & c1) ? y11[q - KHS - 1] : (unsigned short)0;
    }
    #pragma unroll
    for (int it = 0; it < 10; it++) {
        float s = bf2f(v00[it]) + bf2f(v01[it]) + bf2f(v10[it]) + bf2f(v11[it]);
        Wr[threadIdx.x + it*256] = f2bf(s);
    }
}

// ------ KR0: R0e[n=(py*2+px)*64+c][k=v'*49+u'] = b[2v'+py-1, 2u'+px-1, c] ---
// k >= 2401 -> 0 (exact zero padding).
__global__ __launch_bounds__(256) void k_buildR0e(const float* __restrict__ bsrc,
    unsigned short* __restrict__ R0e)
{
    int blk = blockIdx.x;            // nb*256
    int n = blk % 256, bi = blk / 256;
    int c = n & 63, pp = n >> 6;
    int py = pp >> 1, px = pp & 1;
    unsigned short* Rr = R0e + ((size_t)bi*256 + n)*WK;
    for (int k = threadIdx.x; k < WK; k += 256) {
        float val = 0.f;
        if (k < 2401) {
            int vp = k / 49, up = k - vp*49;
            int ry = 2*vp + py - 1, rx = 2*up + px - 1;
            if ((unsigned)ry < KHH && (unsigned)rx < KHH)
                val = bsrc[(((size_t)bi*KHH + ry)*KHH + rx)*KC + c];
        }
        Rr[k] = f2bf(val);
    }
}

// ------ K8': out[iy,ix,c] = 0.25 * sum_{s<8} Pq[s][(Py*49+Px), (py,px,c)] ---
__global__ __launch_bounds__(256) void k_reduce_out(const unsigned short* __restrict__ Pq,
    float* __restrict__ out, size_t psize)
{
    size_t gid = (size_t)blockIdx.x*256 + threadIdx.x;   // nb*96*96*16
    int c4 = (int)(gid & 15)*4;
    size_t r = gid >> 4;
    int ix = (int)(r % KHH); r /= KHH;
    int iy = (int)(r % KHH);
    int bi = (int)(r / KHH);
    int py = (iy & 1) ? 0 : 1;
    int Py = (iy + 1 - py) >> 1;
    int px = (ix & 1) ? 0 : 1;
    int Px = (ix + 1 - px) >> 1;
    size_t base = ((size_t)bi*WM + Py*49 + Px)*256 + ((py*2 + px) << 6) + c4;
    f32x4 acc = (f32x4){0.f,0.f,0.f,0.f};
    #pragma unroll
    for (int s = 0; s < 8; s++) {
        bf16x4 v = *(const bf16x4*)&Pq[base + (size_t)s*psize];
        #pragma unroll
        for (int j = 0; j < 4; j++)
            acc[j] += bf2f((unsigned short)v[j]);
    }
    f32x4 o = acc * 0.25f;
    *(f32x4*)&out[(((size_t)bi*KHH + iy)*KHH + ix)*KC + c4] = o;
}

extern "C" void kernel_launch(void* const* d_in, const int* in_sizes, int n_in,
                              void* d_out, int out_size, void* d_ws, size_t ws_size,
                              hipStream_t stream)
{
    const float* f    = (const float*)d_in[0];
    const float* b    = (const float*)d_in[1];
    const float* mask = (const float*)d_in[2];
    const float* fw   = (const float*)d_in[3];
    float* out = (float*)d_out;

    auto need = [](int nbc) -> size_t {
        return (size_t)nbc * (2ull*KL*KC + 4ull*KL + 2ull*(size_t)KL*KL) * 4ull;
    };
    int nbc = 4;
    if (need(nbc) > ws_size) nbc = 2;
    if (need(nbc) > ws_size) nbc = 1;

    for (int bi0 = 0; bi0 < 4; bi0 += nbc) {
        int nb = (4 - bi0 < nbc) ? (4 - bi0) : nbc;
        const float* fc = f    + (size_t)bi0*KHH*KHH*KC;
        const float* bc = b    + (size_t)bi0*KHH*KHH*KC;
        const float* mc = mask + (size_t)bi0*KHH*KHH;
        float* outc = out + (size_t)bi0*KHH*KHH*KC;

        float* w    = (float*)d_ws;
        float* nbuf = w;  w += (size_t)nbc*KL;
        float* mdd  = w;  w += (size_t)nbc*KL;
        float* rnrm = w;  w += (size_t)nbc*KL;
        float* mmb  = w;  w += (size_t)nbc*KL;
        float* bufA = w;  w += (size_t)nbc*KL*KL;
        float* bufB = w;
        // lifetimes:
        //  bufB: [Ahat|Bhat] (fp16) -> Y1 (fp32) -> [W bf16 | R0e bf16]
        //  bufA: T (fp32) -> Ybf (bf16) -> Pq partials (bf16, after Ybf)
        unsigned short* Ahat = (unsigned short*)bufB;
        unsigned short* Bhat = Ahat + (size_t)nbc*KL*192;
        float* Tbuf = bufA;
        float* Y1   = bufB;
        unsigned short* Ybf = (unsigned short*)bufA;
        unsigned short* Wb  = (unsigned short*)bufB;
        unsigned short* R0e = Wb + (size_t)nbc*WM*WK;
        unsigned short* Pq  = Ybf + (size_t)nbc*KL*KL;  // after Ybf (Ybf dead post-buildW)
        size_t psize = (size_t)nbc*WM*256;   // one split-K partial (elements)

        k_prep2     <<<nb*KL, 64, 0, stream>>>(fc, bc, mc, nbuf, mdd, Ahat, Bhat);
        k_normmask  <<<(nb*KL)/256, 256, 0, stream>>>(nbuf, mdd, rnrm, mmb);
        // T = Ahat * Bhat^T  (K=192 fp16 single-segment, fp32 out)
        k_mfma_bt<6,false,true><<<dim3(18, 18, nb), 256, 0, stream>>>(
            Ahat, Bhat, Tbuf, KL, (size_t)KL*192, (size_t)KL*192, (size_t)KL*KL,
            192, 1, 0);
        // y-diag 3-tap * rnrm + fuse1: T (bufA) -> Y1 (bufB)
        k_fuse_a2   <<<dim3(9, 288, nb), 256, 0, stream>>>(Tbuf, rnrm, fw, Y1);
        // fuse2 + softmax: Y1 (bufB) -> Ybf (bufA)
        k_fuse_b    <<<nb*1152, 256, 0, stream>>>(Y1, fw, mmb, Ybf);
        // W = 2x2 diag box-sum of Y on padded 49x49 grid: Ybf -> W (bufB)
        k_buildW    <<<nb*2401, 256, 0, stream>>>(Ybf, Wb);
        // R0e: 256 parity columns of conv_transpose kernel (exact zero pad)
        k_buildR0e  <<<nb*256, 256, 0, stream>>>(bc, R0e);
        // Pq = W * R0e^T (M=2432, N=256, K=2560, split-K=8, bf16 partials)
        k_mfma_bt<10,true,false><<<dim3(2, 19, nb*8), 256, 0, stream>>>(
            Wb, R0e, Pq, 256, (size_t)WM*WK, (size_t)256*WK, (size_t)WM*256,
            WK, 8, psize);
        // reduce split-K partials + parity scatter + /4 -> out
        k_reduce_out<<<nb*KHH*KHH*16/256, 256, 0, stream>>>(Pq, outc, psize);
    }
}